// Round 3
// baseline (439.289 us; speedup 1.0000x reference)
//
#include <hip/hip_runtime.h>
#include <hip/hip_bf16.h>
#include <cstdint>

#define TSEQ 2048
#define NB   2
#define NH   16
#define NKV  4
#define HD   128
#define EMB  2048
#define WIN  512

typedef unsigned short u16;
typedef __attribute__((ext_vector_type(8))) short s16x8;
typedef __attribute__((ext_vector_type(4))) float f32x4;
typedef __attribute__((ext_vector_type(4))) unsigned short u16x4;

__device__ __forceinline__ u16 f2bf(float x) {
    unsigned u = __builtin_bit_cast(unsigned, x);
    u += 0x7fffu + ((u >> 16) & 1u);
    return (u16)(u >> 16);
}
__device__ __forceinline__ float bf2f(u16 u) {
    return __builtin_bit_cast(float, ((unsigned)u) << 16);
}

__device__ __forceinline__ void gld_lds16(const void* g, void* l) {
    __builtin_amdgcn_global_load_lds(
        (__attribute__((address_space(1))) void*)(void*)(g),
        (__attribute__((address_space(3))) void*)(l),
        16, 0, 0);
}

__device__ __forceinline__ f32x4 mfma16(s16x8 a, s16x8 b, f32x4 c) {
    return __builtin_amdgcn_mfma_f32_16x16x32_bf16(a, b, c, 0, 0, 0);
}

// ---- DPP 16-lane reductions (VALU speed, no LDS pipe) ----
template <int CTRL>
__device__ __forceinline__ float dpp_movf(float x) {
    return __builtin_bit_cast(float,
        __builtin_amdgcn_update_dpp(0, __builtin_bit_cast(int, x), CTRL, 0xF, 0xF, true));
}
__device__ __forceinline__ float dpp_max16(float x) {
    x = fmaxf(x, dpp_movf<0xB1>(x));
    x = fmaxf(x, dpp_movf<0x4E>(x));
    x = fmaxf(x, dpp_movf<0x128>(x));
    x = fmaxf(x, dpp_movf<0x124>(x));
    return x;
}
__device__ __forceinline__ float dpp_sum16(float x) {
    x += dpp_movf<0xB1>(x);
    x += dpp_movf<0x4E>(x);
    x += dpp_movf<0x128>(x);
    x += dpp_movf<0x124>(x);
    return x;
}

// ---------------- fused fp32 -> bf16 casts ----------------
__global__ void cast_all(const float* __restrict__ x,  const float* __restrict__ wq,
                         const float* __restrict__ wk, const float* __restrict__ wv,
                         const float* __restrict__ wo,
                         u16* __restrict__ xb, u16* __restrict__ wqb,
                         u16* __restrict__ wkvb, u16* __restrict__ wob) {
    long i = ((long)blockIdx.x * 256 + threadIdx.x) * 4;
    const float* s; u16* d; long off;
    if (i < 8388608L)        { s = x;  d = xb;             off = i; }
    else if (i < 12582912L)  { s = wq; d = wqb;            off = i - 8388608L; }
    else if (i < 13631488L)  { s = wk; d = wkvb;           off = i - 12582912L; }
    else if (i < 14680064L)  { s = wv; d = wkvb + 1048576; off = i - 13631488L; }
    else                     { s = wo; d = wob;            off = i - 14680064L; }
    float4 v = *(const float4*)(s + off);
    u16x4 o;
    o[0] = f2bf(v.x); o[1] = f2bf(v.y); o[2] = f2bf(v.z); o[3] = f2bf(v.w);
    *(u16x4*)(d + off) = o;
}

// ---------------- rope table: tab[0..131071]=cos(t,d), tab[131072..]=sin(t,d), d<64 ----------------
__global__ void rope_table(float* __restrict__ tab) {
    int i = blockIdx.x * 256 + threadIdx.x;   // 131072 threads
    int t = i >> 6, d = i & 63;
    float inv = __expf(-(float)d * (9.210340371976184f / 64.0f));
    float s, c;
    sincosf((float)t * inv, &s, &c);
    tab[i] = c;
    tab[131072 + i] = s;
}

// ---------------- m97-style bf16 GEMM:  C[M][N] = A[M][K] * B[N][K]^T ----------------
// MODE 0: fp32 out. MODE 1: bf16 out. MODE 2: KV fused (K->stride512, V->vt[b][kv][d][t])
template <int MODE>
__global__ __launch_bounds__(256) void gemm_bt(const u16* __restrict__ A, const u16* __restrict__ B,
                                               void* __restrict__ Cp, u16* __restrict__ vtp,
                                               int M, int N, int K) {
    __shared__ __align__(16) u16 As[128 * 32];
    __shared__ __align__(16) u16 Bs[128 * 32];
    const int tid  = threadIdx.x;
    const int lane = tid & 63;
    const int w    = tid >> 6;
    const int l15  = lane & 15;
    const int quad = lane >> 4;
    const int wr   = w >> 1, wc = w & 1;

    const int srow  = w * 32 + (lane >> 2);
    const int cbyte = (lane & 3) * 16;
    const char* ag0 = (const char*)(A + (size_t)(blockIdx.y * 128 + srow) * K) + cbyte;
    const char* ag1 = ag0 + (size_t)16 * K * 2;
    const char* bg0 = (const char*)(B + (size_t)(blockIdx.x * 128 + srow) * K) + cbyte;
    const char* bg1 = bg0 + (size_t)16 * K * 2;
    char* al0 = (char*)As + (w * 32) * 64;
    char* al1 = al0 + 16 * 64;
    char* bl0 = (char*)Bs + (w * 32) * 64;
    char* bl1 = bl0 + 16 * 64;

    f32x4 acc[4][4];
#pragma unroll
    for (int i = 0; i < 4; i++)
#pragma unroll
        for (int j = 0; j < 4; j++)
            acc[i][j] = f32x4{0.f, 0.f, 0.f, 0.f};

    for (int k0 = 0; k0 < K; k0 += 32) {
        gld_lds16(ag0, al0);
        gld_lds16(ag1, al1);
        gld_lds16(bg0, bl0);
        gld_lds16(bg1, bl1);
        ag0 += 64; ag1 += 64; bg0 += 64; bg1 += 64;
        __syncthreads();
        s16x8 af[4], bf[4];
#pragma unroll
        for (int i = 0; i < 4; i++)
            af[i] = *(const s16x8*)(As + (wr * 64 + i * 16 + l15) * 32 + quad * 8);
#pragma unroll
        for (int j = 0; j < 4; j++)
            bf[j] = *(const s16x8*)(Bs + (wc * 64 + j * 16 + l15) * 32 + quad * 8);
#pragma unroll
        for (int i = 0; i < 4; i++)
#pragma unroll
            for (int j = 0; j < 4; j++)
                acc[i][j] = mfma16(af[i], bf[j], acc[i][j]);
        __syncthreads();
    }

    const int row0 = blockIdx.y * 128 + wr * 64;
    const int col0 = blockIdx.x * 128 + wc * 64 + l15;
#pragma unroll
    for (int i = 0; i < 4; i++) {
        const int trow0 = row0 + i * 16 + quad * 4;
#pragma unroll
        for (int j = 0; j < 4; j++) {
            const int col = col0 + j * 16;
            if (MODE == 0) {
#pragma unroll
                for (int r = 0; r < 4; r++)
                    ((float*)Cp)[(size_t)(trow0 + r) * N + col] = acc[i][j][r];
            } else if (MODE == 1) {
#pragma unroll
                for (int r = 0; r < 4; r++)
                    ((u16*)Cp)[(size_t)(trow0 + r) * N + col] = f2bf(acc[i][j][r]);
            } else {
                if (col < 512) {
#pragma unroll
                    for (int r = 0; r < 4; r++)
                        ((u16*)Cp)[(size_t)(trow0 + r) * 512 + col] = f2bf(acc[i][j][r]);
                } else {
                    const int bb  = trow0 >> 11;
                    const int t0  = trow0 & (TSEQ - 1);
                    const int kvi = (col - 512) >> 7;
                    const int d   = (col - 512) & (HD - 1);
                    u16x4 pk;
#pragma unroll
                    for (int r = 0; r < 4; r++) pk[r] = f2bf(acc[i][j][r]);
                    *(u16x4*)(vtp + ((size_t)((bb * NKV + kvi) * HD + d)) * TSEQ + t0) = pk;
                }
            }
        }
    }
}

// ---------------- RoPE in-place on bf16 K via table ----------------
__global__ void rope_k(u16* __restrict__ buf, const float* __restrict__ tab) {
    int i = blockIdx.x * 256 + threadIdx.x;   // 1048576 threads
    int d   = i & 63;
    int hh  = (i >> 6) & 3;
    int row = i >> 8;
    int t   = row & (TSEQ - 1);
    size_t base = (size_t)row * 512 + hh * HD + d;
    float x1 = bf2f(buf[base]);
    float x2 = bf2f(buf[base + 64]);
    float c = tab[t * 64 + d];
    float s = tab[131072 + t * 64 + d];
    buf[base]      = f2bf(x1 * c - x2 * s);
    buf[base + 64] = f2bf(x2 * c + x1 * s);
}

// ---------------- flash attention, key-split: block = 16-query tile x head; 4 waves split key blocks ----------------
__global__ __launch_bounds__(256) void attn_kernel(const u16* __restrict__ qb, const u16* __restrict__ kb,
                                                   const u16* __restrict__ vt, const float* __restrict__ tab,
                                                   u16* __restrict__ ao) {
    // smem: Of[4][16][132] fp32 (33792B, combine phase) overlaid with Pl[4][1024] u16 (8192B, loop phase);
    //       Lm[4][16], Ll[4][16] fp32 after Of.
    __shared__ __align__(16) char smem[33792 + 512];
    float* Of = (float*)smem;
    float* Lm = (float*)(smem + 33792);
    float* Ll = Lm + 64;
    u16*   Pw = ((u16*)smem) + (threadIdx.x >> 6) * 1024;

    const int lane = threadIdx.x & 63;
    const int w    = threadIdx.x >> 6;
    const int l15  = lane & 15;
    const int quad = lane >> 4;
    const int qt   = blockIdx.x;
    const int h    = blockIdx.y;
    const int b    = blockIdx.z;
    const int q0   = qt * 16;
    const int kv   = h >> 2;
    const float scale = 0.08838834764831845f;   // 1/sqrt(128)

    // ---- Q fragments with fused RoPE from table ----
    s16x8 aq[4];
    {
        const u16* qrow = qb + (size_t)(b * TSEQ + q0 + l15) * EMB + h * HD + quad * 8;
        const float* ct = tab + (size_t)(q0 + l15) * 64 + quad * 8;
        float qf[4][8], cs[2][8], sn[2][8];
        *(float4*)(&cs[0][0]) = *(const float4*)(ct);
        *(float4*)(&cs[0][4]) = *(const float4*)(ct + 4);
        *(float4*)(&cs[1][0]) = *(const float4*)(ct + 32);
        *(float4*)(&cs[1][4]) = *(const float4*)(ct + 36);
        *(float4*)(&sn[0][0]) = *(const float4*)(ct + 131072);
        *(float4*)(&sn[0][4]) = *(const float4*)(ct + 131076);
        *(float4*)(&sn[1][0]) = *(const float4*)(ct + 131104);
        *(float4*)(&sn[1][4]) = *(const float4*)(ct + 131108);
#pragma unroll
        for (int c = 0; c < 4; c++)
#pragma unroll
            for (int e = 0; e < 8; e++)
                qf[c][e] = bf2f(qrow[c * 32 + e]);
#pragma unroll
        for (int c = 0; c < 2; c++)
#pragma unroll
            for (int e = 0; e < 8; e++) {
                float x1 = qf[c][e], x2 = qf[c + 2][e];
                qf[c][e]     = x1 * cs[c][e] - x2 * sn[c][e];
                qf[c + 2][e] = x2 * cs[c][e] + x1 * sn[c][e];
            }
#pragma unroll
        for (int c = 0; c < 4; c++)
#pragma unroll
            for (int e = 0; e < 8; e++)
                aq[c][e] = (short)f2bf(qf[c][e]);
    }

    f32x4 o[8];
#pragma unroll
    for (int n = 0; n < 8; n++) o[n] = f32x4{0.f, 0.f, 0.f, 0.f};
    float mrow[4] = {-1e30f, -1e30f, -1e30f, -1e30f};
    float lrow[4] = {0.f, 0.f, 0.f, 0.f};

    int kb0 = q0 - (WIN - 1);
    if (kb0 < 0) kb0 = 0;
    kb0 &= ~63;

    // wave w takes key-blocks w, w+4, w+8, ... (round-robin)
    for (int kbi = kb0 + w * 64; kbi <= q0 + 15; kbi += 256) {
        // ---- QK^T ----
        const u16* kr = kb + (size_t)(b * TSEQ + kbi + l15) * 512 + kv * HD + quad * 8;
        s16x8 bkf[4][4];
#pragma unroll
        for (int kt = 0; kt < 4; kt++)
#pragma unroll
            for (int c = 0; c < 4; c++)
                bkf[kt][c] = *(const s16x8*)(kr + kt * 16 * 512 + c * 32);
        f32x4 s[4];
#pragma unroll
        for (int kt = 0; kt < 4; kt++) s[kt] = f32x4{0.f, 0.f, 0.f, 0.f};
#pragma unroll
        for (int c = 0; c < 4; c++)
#pragma unroll
            for (int kt = 0; kt < 4; kt++)
                s[kt] = mfma16(aq[c], bkf[kt][c], s[kt]);

        // ---- V prefetch (chunk 0) ----
        const u16* vb = vt + ((size_t)(b * NKV + kv) * HD + l15) * TSEQ + kbi + quad * 8;
        s16x8 vf0[8];
#pragma unroll
        for (int n = 0; n < 8; n++)
            vf0[n] = *(const s16x8*)(vb + (size_t)n * 16 * TSEQ);

        // ---- online softmax ----
        const bool full = (kbi >= q0 - 496) && (kbi + 63 <= q0);  // wave-uniform
        float alpha[4], p[4][4];
#pragma unroll
        for (int r = 0; r < 4; r++) {
            const int row = q0 + quad * 4 + r;
            float v[4];
            if (full) {
#pragma unroll
                for (int kt = 0; kt < 4; kt++) v[kt] = s[kt][r] * scale;
            } else {
#pragma unroll
                for (int kt = 0; kt < 4; kt++) {
                    int cidx = kbi + kt * 16 + l15;
                    v[kt] = (cidx <= row && row - cidx < WIN) ? s[kt][r] * scale : -1e30f;
                }
            }
            float mx = fmaxf(fmaxf(v[0], v[1]), fmaxf(v[2], v[3]));
            mx = dpp_max16(mx);
            float mnew = fmaxf(mrow[r], mx);
            alpha[r] = __expf(mrow[r] - mnew);
            float e0 = __expf(v[0] - mnew);
            float e1 = __expf(v[1] - mnew);
            float e2 = __expf(v[2] - mnew);
            float e3 = __expf(v[3] - mnew);
            float rs = (e0 + e1) + (e2 + e3);
            rs = dpp_sum16(rs);
            lrow[r] = lrow[r] * alpha[r] + rs;
            mrow[r] = mnew;
            p[0][r] = e0; p[1][r] = e1; p[2][r] = e2; p[3][r] = e3;
        }
#pragma unroll
        for (int n = 0; n < 8; n++) {
            o[n][0] *= alpha[0]; o[n][1] *= alpha[1];
            o[n][2] *= alpha[2]; o[n][3] *= alpha[3];
        }

        // ---- P: C-layout -> LDS -> A-layout (per-wave region) ----
#pragma unroll
        for (int r = 0; r < 4; r++)
#pragma unroll
            for (int kt = 0; kt < 4; kt++)
                Pw[(kt >> 1) * 512 + (quad * 4 + r) * 32 + (kt & 1) * 16 + l15] = f2bf(p[kt][r]);
        asm volatile("s_waitcnt lgkmcnt(0)" ::: "memory");
        s16x8 ap0 = *(const s16x8*)(Pw + l15 * 32 + quad * 8);
        s16x8 ap1 = *(const s16x8*)(Pw + 512 + l15 * 32 + quad * 8);

        // ---- PV ----
#pragma unroll
        for (int n = 0; n < 8; n++)
            o[n] = mfma16(ap0, vf0[n], o[n]);
#pragma unroll
        for (int n = 0; n < 8; n++) {
            s16x8 bv = *(const s16x8*)(vb + 32 + (size_t)n * 16 * TSEQ);
            o[n] = mfma16(ap1, bv, o[n]);
        }
    }

    // ---- combine 4 key-partitions across the block ----
    if (l15 == 0) {
#pragma unroll
        for (int r = 0; r < 4; r++) {
            Lm[w * 16 + quad * 4 + r] = mrow[r];
            Ll[w * 16 + quad * 4 + r] = lrow[r];
        }
    }
    __syncthreads();   // Lm/Ll visible; all loop-phase Pl use done

    float Lsum[4], mysc[4];
#pragma unroll
    for (int r = 0; r < 4; r++) {
        const int row = quad * 4 + r;
        float m0 = Lm[row], m1 = Lm[16 + row], m2 = Lm[32 + row], m3 = Lm[48 + row];
        float M = fmaxf(fmaxf(m0, m1), fmaxf(m2, m3));
        Lsum[r] = Ll[row] * __expf(m0 - M) + Ll[16 + row] * __expf(m1 - M) +
                  Ll[32 + row] * __expf(m2 - M) + Ll[48 + row] * __expf(m3 - M);
        mysc[r] = __expf(mrow[r] - M);
    }
#pragma unroll
    for (int n = 0; n < 8; n++)
#pragma unroll
        for (int r = 0; r < 4; r++)
            Of[(w * 16 + quad * 4 + r) * 132 + n * 16 + l15] = o[n][r] * mysc[r];
    __syncthreads();

    // wave w owns output column chunks n = 2w, 2w+1
#pragma unroll
    for (int c = 0; c < 2; c++) {
        const int n = w * 2 + c;
        const int col = n * 16 + l15;
#pragma unroll
        for (int r = 0; r < 4; r++) {
            const int row = quad * 4 + r;
            float val = Of[row * 132 + col] + Of[(16 + row) * 132 + col] +
                        Of[(32 + row) * 132 + col] + Of[(48 + row) * 132 + col];
            ao[(size_t)(b * TSEQ + q0 + row) * EMB + h * HD + col] = f2bf(val / Lsum[r]);
        }
    }
}

extern "C" void kernel_launch(void* const* d_in, const int* in_sizes, int n_in,
                              void* d_out, int out_size, void* d_ws, size_t ws_size,
                              hipStream_t stream) {
    const float* x  = (const float*)d_in[0];
    const float* Wq = (const float*)d_in[1];
    const float* Wk = (const float*)d_in[2];
    const float* Wv = (const float*)d_in[3];
    const float* Wo = (const float*)d_in[4];
    float* out = (float*)d_out;

    u16* ws   = (u16*)d_ws;
    u16* xb   = ws;                 //  8388608  (4096 x 2048)  [reused as ao]
    u16* wqb  = ws + 8388608L;      //  4194304
    u16* wkvb = ws + 12582912L;     //  2097152  rows: Wk then Wv
    u16* wob  = ws + 14680064L;     //  4194304
    u16* qb   = ws + 18874368L;     //  8388608  raw Q (rope fused in attn)
    u16* kbuf = ws + 27262976L;     //  2097152  (4096 x 512) roped K
    u16* vt   = ws + 29360128L;     //  2097152  (b,kv,d,t)
    float* tab = (float*)(ws + 31457280L);  // 262144 floats = 1 MB (cos|sin)
    u16* ao   = xb;
    // total ws: 62914560 + 1048576 = 63963136 B < 64 MB

    rope_table<<<512, 256, 0, stream>>>(tab);
    cast_all<<<18432, 256, 0, stream>>>(x, Wq, Wk, Wv, Wo, xb, wqb, wkvb, wob);

    gemm_bt<1><<<dim3(16, 32), 256, 0, stream>>>(xb, wqb, qb, nullptr, 4096, 2048, 2048);
    gemm_bt<2><<<dim3(8, 32),  256, 0, stream>>>(xb, wkvb, kbuf, vt, 4096, 1024, 2048);

    rope_k<<<4096, 256, 0, stream>>>(kbuf, tab);

    attn_kernel<<<dim3(128, 16, 2), 256, 0, stream>>>(qb, kbuf, vt, tab, ao);

    gemm_bt<0><<<dim3(16, 32), 256, 0, stream>>>(ao, wob, out, nullptr, 4096, 2048, 2048);
}